// Round 10
// baseline (17413.547 us; speedup 1.0000x reference)
//
#include <hip/hip_runtime.h>
#include <hip/hip_fp16.h>

#define NN 4096
#define TOLF 1e-9f
#define MAX_ITER 100
#define NB 512     // persistent blocks = 2/CU x 256 CU (64KiB LDS each)
#define RPB 8      // rows per block

__device__ __forceinline__ float fastrcp(float x) {
    return __builtin_amdgcn_rcpf(x);   // v_rcp_f32, ~1e-6 rel err
}

union H2U { __half2 h; unsigned int u; };

// Convert 16 packed halves (2x uint4) to 16 floats (fully unrolled -> regs)
__device__ __forceinline__ void cvt16(const uint4* k, float* f) {
#pragma unroll
    for (int q = 0; q < 2; ++q) {
        const unsigned int* w = (const unsigned int*)&k[q];
#pragma unroll
        for (int m = 0; m < 4; ++m) {
            H2U hu; hu.u = w[m];
            float2 d = __half22float2(hu.h);
            f[q * 8 + 2 * m]     = d.x;
            f[q * 8 + 2 * m + 1] = d.y;
        }
    }
}

// Grid-wide barrier: monotone epoch counter, device-scope atomics.
// Grid (512 blocks) == exact co-residency capacity (64KiB LDS -> 2 blocks/CU),
// so all blocks are resident and the spin cannot deadlock.
__device__ __forceinline__ void gridbar(unsigned int* cnt, unsigned int target) {
    __syncthreads();
    if (threadIdx.x == 0) {
        __threadfence();   // release: make this block's writes device-visible
        __hip_atomic_fetch_add(cnt, 1u, __ATOMIC_RELEASE, __HIP_MEMORY_SCOPE_AGENT);
        while (__hip_atomic_load(cnt, __ATOMIC_ACQUIRE, __HIP_MEMORY_SCOPE_AGENT) < target)
            __builtin_amdgcn_s_sleep(1);
        __threadfence();   // acquire: see other blocks' writes
    }
    __syncthreads();
}

// Persistent Sinkhorn kernel. Block b owns rows [8b, 8b+8) of K, held in LDS
// as fp16 for all 100 iterations. Pp (= first 512 rows of the P output region)
// is the per-block column-partial buffer; it is dead before the final phase
// overwrites it.
__global__ __launch_bounds__(256) void k_sink(const float* __restrict__ C,
                                              const float* __restrict__ mu,
                                              const float* __restrict__ nu,
                                              float* __restrict__ Pp,   // = P base
                                              float* __restrict__ loss,
                                              float* __restrict__ vacc,
                                              unsigned int* __restrict__ cnt) {
    __shared__ __half Kl[RPB][NN];     // 64 KiB
    __shared__ float wsum[4][RPB];
    __shared__ float wred[4][RPB];
    __shared__ float ush[RPB];

    const int t  = threadIdx.x;
    const int b  = blockIdx.x;
    const int r0 = b * RPB;
    const int c0 = t * 16;
    const int lane = t & 63, wid = t >> 6;

    // ---- load once: Kl[r][:] = fp16(exp(-10*C[r0+r][:])) ----
#pragma unroll
    for (int r = 0; r < RPB; ++r) {
        const float4* Cr = (const float4*)(C + (size_t)(r0 + r) * NN);
#pragma unroll
        for (int q = 0; q < 4; ++q) {
            int i4 = t + q * 256;
            float4 c = Cr[i4];
            H2U h0, h1;
            h0.h = __floats2half2_rn(__expf(-10.f * c.x), __expf(-10.f * c.y));
            h1.h = __floats2half2_rn(__expf(-10.f * c.z), __expf(-10.f * c.w));
            uint2 o; o.x = h0.u; o.y = h1.u;
            ((uint2*)&Kl[r][0])[i4] = o;
        }
    }
    __syncthreads();

    float v[16];
    unsigned int barid = 0;

    for (int it = 0; it < MAX_ITER; ++it) {
        // ---- A: v slice (regs), row dots from LDS -> u (block-local) ----
        if (it == 0) {
#pragma unroll
            for (int s = 0; s < 16; ++s) v[s] = 1.f;
        } else {
            const float4* nu4 = (const float4*)(nu + c0);
            const float4* va4 = (const float4*)(vacc + c0);
#pragma unroll
            for (int q = 0; q < 4; ++q) {
                float4 n = nu4[q];
                float4 p = va4[q];
                v[4 * q + 0] = n.x * fastrcp(p.x + TOLF);
                v[4 * q + 1] = n.y * fastrcp(p.y + TOLF);
                v[4 * q + 2] = n.z * fastrcp(p.z + TOLF);
                v[4 * q + 3] = n.w * fastrcp(p.w + TOLF);
            }
        }
        float part[RPB];
#pragma unroll
        for (int r = 0; r < RPB; ++r) {
            const uint4* lp = (const uint4*)&Kl[r][c0];
            uint4 kr[2]; kr[0] = lp[0]; kr[1] = lp[1];
            float f[16]; cvt16(kr, f);
            float a = 0.f;
#pragma unroll
            for (int s = 0; s < 16; ++s) a += f[s] * v[s];
            part[r] = a;
        }
#pragma unroll
        for (int r = 0; r < RPB; ++r) {
#pragma unroll
            for (int off = 32; off > 0; off >>= 1)
                part[r] += __shfl_xor(part[r], off);
        }
        if (lane == 0) {
#pragma unroll
            for (int r = 0; r < RPB; ++r) wsum[wid][r] = part[r];
        }
        __syncthreads();
        if (t < RPB) {
            float s = wsum[0][t] + wsum[1][t] + wsum[2][t] + wsum[3][t];
            ush[t] = mu[r0 + t] * fastrcp(s + TOLF);
        }
        __syncthreads();

        // ---- B: column partials of this block's 8 rows -> Pp[b][:] ----
        {
            float ur[RPB];
#pragma unroll
            for (int r = 0; r < RPB; ++r) ur[r] = ush[r];
            float pp[16];
#pragma unroll
            for (int s = 0; s < 16; ++s) pp[s] = 0.f;
#pragma unroll
            for (int r = 0; r < RPB; ++r) {
                const uint4* lp = (const uint4*)&Kl[r][c0];
                uint4 kr[2]; kr[0] = lp[0]; kr[1] = lp[1];
                float f[16]; cvt16(kr, f);
#pragma unroll
                for (int s = 0; s < 16; ++s) pp[s] += ur[r] * f[s];
            }
            float4* out = (float4*)(Pp + (size_t)b * NN + c0);
#pragma unroll
            for (int q = 0; q < 4; ++q) {
                float4 o;
                o.x = pp[4 * q + 0]; o.y = pp[4 * q + 1];
                o.z = pp[4 * q + 2]; o.w = pp[4 * q + 3];
                out[q] = o;
            }
        }
        gridbar(cnt, NB * (++barid));   // SYNC1: all partials visible

        // ---- C: reduce columns [8b, 8b+8) over 512 partial rows -> vacc ----
        {
            const int j0 = b * RPB;
            const float4* p0 = (const float4*)(Pp + (size_t)t * NN + j0);
            const float4* p1 = (const float4*)(Pp + (size_t)(t + 256) * NN + j0);
            float4 a0 = p0[0], a1 = p0[1];
            float4 b0 = p1[0], b1 = p1[1];
            float pr[RPB] = {a0.x + b0.x, a0.y + b0.y, a0.z + b0.z, a0.w + b0.w,
                             a1.x + b1.x, a1.y + b1.y, a1.z + b1.z, a1.w + b1.w};
#pragma unroll
            for (int m = 0; m < RPB; ++m) {
#pragma unroll
                for (int off = 32; off > 0; off >>= 1)
                    pr[m] += __shfl_xor(pr[m], off);
            }
            if (lane == 0) {
#pragma unroll
                for (int m = 0; m < RPB; ++m) wred[wid][m] = pr[m];
            }
            __syncthreads();
            if (t < RPB)
                vacc[j0 + t] = wred[0][t] + wred[1][t] + wred[2][t] + wred[3][t];
        }
        gridbar(cnt, NB * (++barid));   // SYNC2: vacc complete
    }

    // ---- final: P = u*exp(-10C)*v (fp32), loss = sum P*|mu_i - nu_j| ----
    {
        float nuv[16];
        const float4* nu4 = (const float4*)(nu + c0);
        const float4* va4 = (const float4*)(vacc + c0);
#pragma unroll
        for (int q = 0; q < 4; ++q) {
            float4 n = nu4[q];
            float4 p = va4[q];
            nuv[4 * q + 0] = n.x; nuv[4 * q + 1] = n.y;
            nuv[4 * q + 2] = n.z; nuv[4 * q + 3] = n.w;
            v[4 * q + 0] = n.x * fastrcp(p.x + TOLF);
            v[4 * q + 1] = n.y * fastrcp(p.y + TOLF);
            v[4 * q + 2] = n.z * fastrcp(p.z + TOLF);
            v[4 * q + 3] = n.w * fastrcp(p.w + TOLF);
        }
        float lacc = 0.f;
#pragma unroll
        for (int r = 0; r < RPB; ++r) {
            const float u_  = ush[r];          // final u, persisted in LDS
            const float mur = mu[r0 + r];
            const float4* Cr = (const float4*)(C + (size_t)(r0 + r) * NN + c0);
            float4* Pr       = (float4*)(Pp + (size_t)(r0 + r) * NN + c0);
#pragma unroll
            for (int q = 0; q < 4; ++q) {
                float4 c = Cr[q];
                float4 p;
                p.x = u_ * __expf(-10.f * c.x) * v[4 * q + 0];
                p.y = u_ * __expf(-10.f * c.y) * v[4 * q + 1];
                p.z = u_ * __expf(-10.f * c.z) * v[4 * q + 2];
                p.w = u_ * __expf(-10.f * c.w) * v[4 * q + 3];
                Pr[q] = p;
                lacc += p.x * fabsf(mur - nuv[4 * q + 0]) +
                        p.y * fabsf(mur - nuv[4 * q + 1]) +
                        p.z * fabsf(mur - nuv[4 * q + 2]) +
                        p.w * fabsf(mur - nuv[4 * q + 3]);
            }
        }
#pragma unroll
        for (int off = 32; off > 0; off >>= 1) lacc += __shfl_xor(lacc, off);
        if (lane == 0) wsum[wid][0] = lacc;
        __syncthreads();
        if (t == 0)
            atomicAdd(loss, wsum[0][0] + wsum[1][0] + wsum[2][0] + wsum[3][0]);
    }
}

extern "C" void kernel_launch(void* const* d_in, const int* in_sizes, int n_in,
                              void* d_out, int out_size, void* d_ws, size_t ws_size,
                              hipStream_t stream) {
    const float* mu = (const float*)d_in[0];
    const float* nu = (const float*)d_in[1];
    const float* C  = (const float*)d_in[2];

    float* P    = (float*)d_out;
    float* loss = P + (size_t)NN * NN;

    float* vacc = (float*)d_ws;                       // 4096 floats
    unsigned int* cnt = (unsigned int*)((float*)d_ws + NN);

    hipMemsetAsync(cnt, 0, sizeof(unsigned int), stream);
    hipMemsetAsync(loss, 0, sizeof(float), stream);
    k_sink<<<NB, 256, 0, stream>>>(C, mu, nu, P, loss, vacc, cnt);
}

// Round 11
// 1706.972 us; speedup vs baseline: 10.2014x; 10.2014x over previous
//
#include <hip/hip_runtime.h>
#include <hip/hip_fp16.h>

#define NN 4096
#define TOLF 1e-9f
#define MAX_ITER 100
#define RPB 8      // rows (or cols) per block in k_u/k_col -> 512 blocks
#define RPBF 4     // rows per block in k_final             -> 1024 blocks
#define TS 64      // transpose tile

__device__ __forceinline__ float fastrcp(float x) {
    return __builtin_amdgcn_rcpf(x);   // v_rcp_f32, ~1e-6 rel err
}

union H2U { __half2 h; unsigned int u; };

// Convert 16 packed halves (2x uint4) to 16 floats (fully unrolled -> regs)
__device__ __forceinline__ void cvt16(const uint4* k, float* f) {
#pragma unroll
    for (int q = 0; q < 2; ++q) {
        const unsigned int* w = (const unsigned int*)&k[q];
#pragma unroll
        for (int m = 0; m < 4; ++m) {
            H2U hu; hu.u = w[m];
            float2 d = __half22float2(hu.h);
            f[q * 8 + 2 * m]     = d.x;
            f[q * 8 + 2 * m + 1] = d.y;
        }
    }
}

// Kh = fp16(exp(-10C)) row-major AND KhT = its transpose (LDS-tiled 64x64).
// Also zeroes loss. Grid: 64x64 tiles -> 4096 blocks.
__global__ __launch_bounds__(256) void k_init(const float* __restrict__ C,
                                              __half* __restrict__ Kh,
                                              __half* __restrict__ KhT,
                                              float* __restrict__ loss) {
    __shared__ __half tile[TS][TS + 1];   // stride 65 halves -> 2-way bank alias (free)
    const int t  = threadIdx.x;
    const int bx = blockIdx.x & 63;       // col tile
    const int by = blockIdx.x >> 6;       // row tile
    const int i0 = by * TS, j0 = bx * TS;

#pragma unroll 4
    for (int rr = 0; rr < 16; ++rr) {     // 4 rows per pass (256 thr / 64 cols)
        int r = rr * 4 + (t >> 6);
        int c = t & 63;
        float x = C[(size_t)(i0 + r) * NN + j0 + c];
        __half h = __float2half_rn(__expf(-10.f * x));
        tile[r][c] = h;
        Kh[(size_t)(i0 + r) * NN + j0 + c] = h;
    }
    __syncthreads();
#pragma unroll 4
    for (int rr = 0; rr < 16; ++rr) {
        int j = rr * 4 + (t >> 6);
        int i = t & 63;
        KhT[(size_t)(j0 + j) * NN + i0 + i] = tile[i][j];
    }
    if (blockIdx.x == 0 && t == 0) *loss = 0.f;
}

// Row phase: u_i = mu_i / (K[i,:].v + tol), v_j = nu_j/(vacc_j + tol) in regs.
// 512 blocks x 256 thr, 8 rows/block, thread owns 16 contiguous columns.
__global__ __launch_bounds__(256, 4) void k_u(const __half* __restrict__ Kh,
                                              const float* __restrict__ mu,
                                              const float* __restrict__ nu,
                                              const float* __restrict__ vacc,
                                              float* __restrict__ uG,
                                              int first) {
    const int t  = threadIdx.x;
    const int b  = blockIdx.x;
    const int r0 = b * RPB;
    const int c0 = t * 16;

    __shared__ float wsum[4][RPB];

    float v[16];
    if (first) {
#pragma unroll
        for (int s = 0; s < 16; ++s) v[s] = 1.f;
    } else {
        const float4* nu4 = (const float4*)(nu + c0);
        const float4* va4 = (const float4*)(vacc + c0);
#pragma unroll
        for (int q = 0; q < 4; ++q) {
            float4 n = nu4[q];
            float4 p = va4[q];
            v[4 * q + 0] = n.x * fastrcp(p.x + TOLF);
            v[4 * q + 1] = n.y * fastrcp(p.y + TOLF);
            v[4 * q + 2] = n.z * fastrcp(p.z + TOLF);
            v[4 * q + 3] = n.w * fastrcp(p.w + TOLF);
        }
    }

    float part[RPB];
#pragma unroll
    for (int r = 0; r < RPB; ++r) {
        const uint4* rowp = (const uint4*)(Kh + (size_t)(r0 + r) * NN + c0);
        uint4 kr[2];
        kr[0] = rowp[0];
        kr[1] = rowp[1];
        float f[16];
        cvt16(kr, f);
        float acc = 0.f;
#pragma unroll
        for (int s = 0; s < 16; ++s) acc += f[s] * v[s];
        part[r] = acc;
    }

#pragma unroll
    for (int r = 0; r < RPB; ++r) {
#pragma unroll
        for (int off = 32; off > 0; off >>= 1)
            part[r] += __shfl_xor(part[r], off);
    }
    const int lane = t & 63, wid = t >> 6;
    if (lane == 0) {
#pragma unroll
        for (int r = 0; r < RPB; ++r) wsum[wid][r] = part[r];
    }
    __syncthreads();
    if (t < RPB) {
        float s = wsum[0][t] + wsum[1][t] + wsum[2][t] + wsum[3][t];
        uG[r0 + t] = mu[r0 + t] * fastrcp(s + TOLF);
    }
}

// Column phase via KhT: vacc[j] = sum_i u_i * K[i,j] = KhT[j,:].u
// Identical structure to k_u: 512 blocks, 8 KhT-rows each, coalesced 16B/lane,
// direct write (no atomics, no zeroing).
__global__ __launch_bounds__(256, 4) void k_col(const __half* __restrict__ KhT,
                                                const float* __restrict__ uG,
                                                float* __restrict__ vacc) {
    const int t  = threadIdx.x;
    const int b  = blockIdx.x;
    const int j0 = b * RPB;
    const int c0 = t * 16;

    __shared__ float wsum[4][RPB];

    float u[16];
    {
        const float4* u4 = (const float4*)(uG + c0);
#pragma unroll
        for (int q = 0; q < 4; ++q) {
            float4 a = u4[q];
            u[4 * q + 0] = a.x; u[4 * q + 1] = a.y;
            u[4 * q + 2] = a.z; u[4 * q + 3] = a.w;
        }
    }

    float part[RPB];
#pragma unroll
    for (int j = 0; j < RPB; ++j) {
        const uint4* rowp = (const uint4*)(KhT + (size_t)(j0 + j) * NN + c0);
        uint4 kr[2];
        kr[0] = rowp[0];
        kr[1] = rowp[1];
        float f[16];
        cvt16(kr, f);
        float acc = 0.f;
#pragma unroll
        for (int s = 0; s < 16; ++s) acc += f[s] * u[s];
        part[j] = acc;
    }

#pragma unroll
    for (int j = 0; j < RPB; ++j) {
#pragma unroll
        for (int off = 32; off > 0; off >>= 1)
            part[j] += __shfl_xor(part[j], off);
    }
    const int lane = t & 63, wid = t >> 6;
    if (lane == 0) {
#pragma unroll
        for (int j = 0; j < RPB; ++j) wsum[wid][j] = part[j];
    }
    __syncthreads();
    if (t < RPB)
        vacc[j0 + t] = wsum[0][t] + wsum[1][t] + wsum[2][t] + wsum[3][t];
}

// P[i][j] = u_i * exp(-10*C_ij) * v_j  (fp32 recompute from C); loss = sum P*|mu_i-nu_j|
__global__ __launch_bounds__(256) void k_final(const float* __restrict__ C,
                                               const float* __restrict__ mu,
                                               const float* __restrict__ nu,
                                               const float* __restrict__ uG,
                                               const float* __restrict__ vlast,
                                               float* __restrict__ P,
                                               float* __restrict__ loss) {
    const int t  = threadIdx.x;
    const int b  = blockIdx.x;
    const int r0 = b * RPBF;
    const int c0 = t * 16;

    __shared__ float ls[4];

    float v[16], nuv[16];
    const float4* nu4 = (const float4*)(nu + c0);
    const float4* vl4 = (const float4*)(vlast + c0);
#pragma unroll
    for (int q = 0; q < 4; ++q) {
        float4 n = nu4[q];
        float4 p = vl4[q];
        nuv[4 * q + 0] = n.x; nuv[4 * q + 1] = n.y;
        nuv[4 * q + 2] = n.z; nuv[4 * q + 3] = n.w;
        v[4 * q + 0] = n.x * fastrcp(p.x + TOLF);
        v[4 * q + 1] = n.y * fastrcp(p.y + TOLF);
        v[4 * q + 2] = n.z * fastrcp(p.z + TOLF);
        v[4 * q + 3] = n.w * fastrcp(p.w + TOLF);
    }

    float lacc = 0.f;
#pragma unroll
    for (int r = 0; r < RPBF; ++r) {
        const float ur  = uG[r0 + r];
        const float mur = mu[r0 + r];
        const float4* Cr = (const float4*)(C + (size_t)(r0 + r) * NN + c0);
        float4* Pr       = (float4*)(P + (size_t)(r0 + r) * NN + c0);
#pragma unroll
        for (int q = 0; q < 4; ++q) {
            float4 c = Cr[q];
            float4 p;
            p.x = ur * __expf(-10.f * c.x) * v[4 * q + 0];
            p.y = ur * __expf(-10.f * c.y) * v[4 * q + 1];
            p.z = ur * __expf(-10.f * c.z) * v[4 * q + 2];
            p.w = ur * __expf(-10.f * c.w) * v[4 * q + 3];
            Pr[q] = p;
            lacc += p.x * fabsf(mur - nuv[4 * q + 0]) +
                    p.y * fabsf(mur - nuv[4 * q + 1]) +
                    p.z * fabsf(mur - nuv[4 * q + 2]) +
                    p.w * fabsf(mur - nuv[4 * q + 3]);
        }
    }
#pragma unroll
    for (int off = 32; off > 0; off >>= 1) lacc += __shfl_xor(lacc, off);
    const int lane = t & 63, wid = t >> 6;
    if (lane == 0) ls[wid] = lacc;
    __syncthreads();
    if (t == 0) atomicAdd(loss, ls[0] + ls[1] + ls[2] + ls[3]);
}

extern "C" void kernel_launch(void* const* d_in, const int* in_sizes, int n_in,
                              void* d_out, int out_size, void* d_ws, size_t ws_size,
                              hipStream_t stream) {
    const float* mu = (const float*)d_in[0];
    const float* nu = (const float*)d_in[1];
    const float* C  = (const float*)d_in[2];

    float* P    = (float*)d_out;
    float* loss = P + (size_t)NN * NN;
    // fp16 K (32 MiB) and K^T (32 MiB) both live inside the 64 MiB P region;
    // k_final never reads them, so the final P overwrite is race-free.
    __half* Kh  = (__half*)d_out;
    __half* KhT = (__half*)((char*)d_out + (size_t)32 * 1024 * 1024);

    float* ws   = (float*)d_ws;
    float* vacc = ws;                // 4096 (single buffer: stream-ordered rw)
    float* uG   = ws + NN;           // 4096

    k_init<<<4096, 256, 0, stream>>>(C, Kh, KhT, loss);

    for (int t = 0; t < MAX_ITER; ++t) {
        k_u  <<<NN / RPB, 256, 0, stream>>>(Kh, mu, nu, vacc, uG, t == 0 ? 1 : 0);
        k_col<<<NN / RPB, 256, 0, stream>>>(KhT, uG, vacc);
    }

    k_final<<<NN / RPBF, 256, 0, stream>>>(C, mu, nu, uG, vacc, P, loss);
}